// Round 7
// baseline (998.026 us; speedup 1.0000x reference)
//
#include <hip/hip_runtime.h>
#include <hip/hip_bf16.h>

typedef __hip_bfloat16 bf16;
typedef __attribute__((ext_vector_type(8))) short short8;   // 8 bf16 (4 VGPRs)
typedef __attribute__((ext_vector_type(4))) float f32x4;
typedef __attribute__((ext_vector_type(4))) unsigned u32x4;

#define NA 100000
#define NT 300000
#define NG 2000
#define EPT 600000
#define ETG 400000

#define DSB 64   // degree-sort blocks
#define DBK 64   // degree buckets (deg capped at DBK-1)

// DPP control codes
#define DPP_QX1 0xB1   // quad_perm [1,0,3,2]  (xor 1)
#define DPP_QX2 0x4E   // quad_perm [2,3,0,1]  (xor 2)
#define DPP_RR4 0x124  // row_ror:4
#define DPP_RR8 0x128  // row_ror:8

template <int CTRL>
__device__ __forceinline__ float dppadd(float x) {
    int y = __builtin_amdgcn_update_dpp(0, __float_as_int(x), CTRL, 0xf, 0xf, true);
    return x + __int_as_float(y);
}

__device__ __forceinline__ float b2f(short s) {
    return __uint_as_float(((unsigned)(unsigned short)s) << 16);
}
__device__ __forceinline__ void cvt16(short8 a, short8 b, float* f) {
#pragma unroll
    for (int j = 0; j < 8; ++j) f[j] = b2f(a[j]);
#pragma unroll
    for (int j = 0; j < 8; ++j) f[8 + j] = b2f(b[j]);
}
__device__ __forceinline__ short f2bs(float x) {
    return (short)__builtin_bit_cast(unsigned short, __float2bfloat16(x));
}

__global__ void fill_u32(unsigned* __restrict__ p, unsigned v, long n) {
    long i = (long)blockIdx.x * 256 + threadIdx.x;
    if (i < n) p[i] = v;
}

// ---------------------------------------------------------------------------
// wprep: fused (We@Wl) -> bf16 MFMA-fragment order, + combined bias.
// COLUMN RELABEL: MFMA col-index c of tile nt holds actual column c*16+nt,
// so in tformf each lane's 16 acc[nt] values are 16 CONSECUTIVE output cols
// (coalesced packed stores). Frag pos: idx = (((ks*16+nt)*4+kb)*16+c)*8+j
// holds Wc[(ks*32+kb*8+j)*256 + (c*16+nt)].
// Block 0 additionally computes bc[256] = be@Wl + bl.
// ---------------------------------------------------------------------------
__global__ __launch_bounds__(256) void wprep(
    const float* __restrict__ We, const float* __restrict__ Wl,
    const float* __restrict__ bl, const float* __restrict__ be,
    short* __restrict__ Bf, float* __restrict__ bc, int KS)
{
    int t = blockIdx.x * 256 + threadIdx.x;
    if (t < KS * 1024) {
        int c = t & 15, kb = (t >> 4) & 3, nt = (t >> 6) & 15, ks = t >> 10;
        int k0 = ks * 32 + kb * 8, n = c * 16 + nt;     // relabeled column
        short8 o;
#pragma unroll
        for (int j = 0; j < 8; ++j) {
            int k = k0 + j;
            float acc = 0.f;
            for (int cc = 0; cc < 64; ++cc)
                acc = fmaf(We[k * 64 + cc], Wl[cc * 256 + n], acc);
            o[j] = f2bs(acc);
        }
        ((short8*)Bf)[t] = o;
    }
    if (blockIdx.x == 0) {
        int j = threadIdx.x;
        float acc = bl[j];
        for (int cc = 0; cc < 64; ++cc) acc = fmaf(be[cc], Wl[cc * 256 + j], acc);
        bc[j] = acc;
    }
}

// ---------------------------------------------------------------------------
// tformf: C[M x 256] = bf16(A[M x K] f32) @ B (bf16 frag-ordered) + bias, MFMA.
// Lane (lrow) holds output cols lrow*16 .. lrow*16+15 across acc[nt] -> pack
// into 8 u32 and store two dwordx4 per row (coalesced, no write-amp).
// ---------------------------------------------------------------------------
template <int KS>
__global__ __launch_bounds__(256) void tformf(
    const float* __restrict__ A, const short* __restrict__ Bf,
    const float* __restrict__ bias, bf16* __restrict__ C, int M)
{
    constexpr int K = KS * 32;
    int wv = threadIdx.x >> 6, lane = threadIdx.x & 63;
    int lrow = lane & 15, kb = lane >> 4;
    int base = blockIdx.x * 64 + wv * 16;

    int arow = base + lrow; if (arow >= M) arow = M - 1;
    const float* Ap = A + (size_t)arow * K + kb * 8;
    short8 a[KS];
#pragma unroll
    for (int s = 0; s < KS; ++s) {
        f32x4 lo = *(const f32x4*)(Ap + s * 32);
        f32x4 hi = *(const f32x4*)(Ap + s * 32 + 4);
#pragma unroll
        for (int j = 0; j < 4; ++j) {
            a[s][j]     = f2bs(lo[j]);
            a[s][4 + j] = f2bs(hi[j]);
        }
    }

    const short8* Bl = (const short8*)Bf + kb * 16 + lrow;

    f32x4 acc[16];
#pragma unroll
    for (int nt = 0; nt < 16; ++nt) {
        float bv = bias[lrow * 16 + nt];     // relabeled column
        f32x4 bvv = {bv, bv, bv, bv};
        acc[nt] = bvv;
    }
#pragma unroll
    for (int nt = 0; nt < 16; ++nt) {
#pragma unroll
        for (int s = 0; s < KS; ++s)
            acc[nt] = __builtin_amdgcn_mfma_f32_16x16x32_bf16(
                a[s], Bl[(s * 16 + nt) * 64], acc[nt], 0, 0, 0);
    }
    int r0 = base + kb * 4;
#pragma unroll
    for (int r = 0; r < 4; ++r) {
        int row = r0 + r;
        if (row >= M) continue;
        unsigned w[8];
#pragma unroll
        for (int n4 = 0; n4 < 8; ++n4) {
            unsigned lo = (unsigned)(unsigned short)f2bs(acc[2 * n4][r]);
            unsigned hi = (unsigned)(unsigned short)f2bs(acc[2 * n4 + 1][r]);
            w[n4] = lo | (hi << 16);
        }
        u32x4 v0 = {w[0], w[1], w[2], w[3]};
        u32x4 v1 = {w[4], w[5], w[6], w[7]};
        u32x4* dst = (u32x4*)(C + (size_t)row * 256 + lrow * 16);
        dst[0] = v0;
        dst[1] = v1;
    }
}

// ============================ edge sort (CSR by dst) ========================
__global__ __launch_bounds__(256) void histo(
    const int* __restrict__ dst, unsigned* __restrict__ cnt, int base, int E)
{
    int i = blockIdx.x * 256 + threadIdx.x;
    if (i < E) atomicAdd(&cnt[base + dst[i]], 1u);
}

__global__ __launch_bounds__(256) void scan_a(
    const unsigned* __restrict__ in, unsigned* __restrict__ out,
    unsigned* __restrict__ part, int n)
{
    __shared__ unsigned ts[256];
    int t = threadIdx.x;
    long base = (long)blockIdx.x * 1024 + (long)t * 4;
    unsigned v0 = 0, v1 = 0, v2 = 0, v3 = 0;
    if (base + 0 < n) v0 = in[base + 0];
    if (base + 1 < n) v1 = in[base + 1];
    if (base + 2 < n) v2 = in[base + 2];
    if (base + 3 < n) v3 = in[base + 3];
    unsigned s = v0 + v1 + v2 + v3;
    ts[t] = s;
    __syncthreads();
    unsigned run = s;
    for (int off = 1; off < 256; off <<= 1) {
        unsigned y = (t >= off) ? ts[t - off] : 0u;
        __syncthreads();
        run += y; ts[t] = run;
        __syncthreads();
    }
    unsigned ex = run - s;
    if (base + 0 < n) out[base + 0] = ex;
    if (base + 1 < n) out[base + 1] = ex + v0;
    if (base + 2 < n) out[base + 2] = ex + v0 + v1;
    if (base + 3 < n) out[base + 3] = ex + v0 + v1 + v2;
    if (t == 255) part[blockIdx.x] = run;
}

__global__ __launch_bounds__(256) void scan_c(
    unsigned* __restrict__ rp, const unsigned* __restrict__ part,
    unsigned* __restrict__ cur, int n)
{
    long i = (long)blockIdx.x * 256 + threadIdx.x;
    if (i >= n) return;
    unsigned v = rp[i] + part[i >> 10];
    rp[i] = v;
    if (i < n - 1) cur[i] = v;
}

__global__ __launch_bounds__(256) void scat(
    const int* __restrict__ src, const int* __restrict__ dst,
    unsigned* __restrict__ cur, int base, int* __restrict__ ss, int E)
{
    int i = blockIdx.x * 256 + threadIdx.x;
    if (i < E) {
        unsigned p = atomicAdd(&cur[base + dst[i]], 1u);
        ss[p] = src[i];
    }
}

// ======== contention-free degree sort (pt dsts -> order[]) ========
__global__ __launch_bounds__(256) void deg_cnt(
    const unsigned* __restrict__ rp, unsigned* __restrict__ bcnt, int n)
{
    __shared__ unsigned hcnt[DBK];
    int b = blockIdx.x;
    int chunk = (n + DSB - 1) / DSB;
    int lo = b * chunk, hi = min(n, lo + chunk);
    if (threadIdx.x < DBK) hcnt[threadIdx.x] = 0u;
    __syncthreads();
    for (int i = lo + threadIdx.x; i < hi; i += 256) {
        unsigned deg = rp[i + 1] - rp[i];
        if (deg > DBK - 1) deg = DBK - 1;
        atomicAdd(&hcnt[deg], 1u);          // LDS atomic: intra-block only
    }
    __syncthreads();
    if (threadIdx.x < DBK) bcnt[(size_t)threadIdx.x * DSB + b] = hcnt[threadIdx.x];
}

__global__ __launch_bounds__(256) void scan4k(
    const unsigned* __restrict__ in, unsigned* __restrict__ out)
{
    __shared__ unsigned ts[256];
    int t = threadIdx.x;
    unsigned v[16]; unsigned s = 0;
#pragma unroll
    for (int j = 0; j < 16; ++j) { v[j] = in[t * 16 + j]; s += v[j]; }
    ts[t] = s;
    __syncthreads();
    unsigned run = s;
    for (int off = 1; off < 256; off <<= 1) {
        unsigned y = (t >= off) ? ts[t - off] : 0u;
        __syncthreads();
        run += y; ts[t] = run;
        __syncthreads();
    }
    unsigned ex = run - s;
#pragma unroll
    for (int j = 0; j < 16; ++j) { out[t * 16 + j] = ex; ex += v[j]; }
}

__global__ __launch_bounds__(256) void deg_place(
    const unsigned* __restrict__ rp, const unsigned* __restrict__ base,
    int* __restrict__ order, int n)
{
    __shared__ unsigned hcur[DBK];
    int b = blockIdx.x;
    int chunk = (n + DSB - 1) / DSB;
    int lo = b * chunk, hi = min(n, lo + chunk);
    if (threadIdx.x < DBK) hcur[threadIdx.x] = base[(size_t)threadIdx.x * DSB + b];
    __syncthreads();
    for (int i = lo + threadIdx.x; i < hi; i += 256) {
        unsigned deg = rp[i + 1] - rp[i];
        if (deg > DBK - 1) deg = DBK - 1;
        unsigned p = atomicAdd(&hcur[deg], 1u);   // LDS atomic
        order[p] = i;
    }
}

// ---------------------------------------------------------------------------
// gat_w: fused GATv2 (track phase), 16-lane-group per dst (4 dst per wave),
// degree-sorted order; deg-0 fast path; edge loop unrolled 2x (odd peel +
// pairs: 2 independent gl loads / dots / exps, halved acc chain depth).
// Epilogue fuses bias+elu+64x64 linear+l2norm+store.
// ---------------------------------------------------------------------------
__global__ __launch_bounds__(256) void gat_w(
    const bf16* __restrict__ gl, const bf16* __restrict__ gr,
    const int* __restrict__ ssrc, const unsigned* __restrict__ rp,
    const int* __restrict__ order,
    const float* __restrict__ att, const float* __restrict__ bias,
    const float* __restrict__ linW, const float* __restrict__ linb,
    float* __restrict__ outp, int Nd)
{
    __shared__ float WL[4096];        // linW [c][j] row-major
    __shared__ float bL[64];
    __shared__ float hC[64];          // deg-0 constant h
    __shared__ float hL[16][68];      // per-group h, padded
    for (int t = threadIdx.x; t < 4096; t += 256) WL[t] = linW[t];
    if (threadIdx.x < 64) {
        float b = bias[threadIdx.x];
        bL[threadIdx.x] = b;
        hC[threadIdx.x] = b > 0.f ? b : (__expf(b) - 1.f);
    }
    __syncthreads();

    int grp = threadIdx.x >> 4, g = threadIdx.x & 15;
    int h = g & 3, q = g >> 2;
    int eoff = h * 64 + q * 16;

    float at[16];
#pragma unroll
    for (int j = 0; j < 16; ++j) at[j] = att[eoff + j];
    f32x4 lbv = *(const f32x4*)(linb + g * 4);

    // ---- precompute deg-0 constant output (normalized) ----
    f32x4 ycn;
    {
        float y0 = lbv[0], y1 = lbv[1], y2 = lbv[2], y3 = lbv[3];
#pragma unroll
        for (int c = 0; c < 64; c += 4) {
            f32x4 hv = *(const f32x4*)&hC[c];
            const float* wr = WL + c * 64 + g * 4;
            f32x4 w0 = *(const f32x4*)(wr);
            f32x4 w1 = *(const f32x4*)(wr + 64);
            f32x4 w2 = *(const f32x4*)(wr + 128);
            f32x4 w3 = *(const f32x4*)(wr + 192);
            y0 = fmaf(hv[0], w0[0], y0); y1 = fmaf(hv[0], w0[1], y1);
            y2 = fmaf(hv[0], w0[2], y2); y3 = fmaf(hv[0], w0[3], y3);
            y0 = fmaf(hv[1], w1[0], y0); y1 = fmaf(hv[1], w1[1], y1);
            y2 = fmaf(hv[1], w1[2], y2); y3 = fmaf(hv[1], w1[3], y3);
            y0 = fmaf(hv[2], w2[0], y0); y1 = fmaf(hv[2], w2[1], y1);
            y2 = fmaf(hv[2], w2[2], y2); y3 = fmaf(hv[2], w2[3], y3);
            y0 = fmaf(hv[3], w3[0], y0); y1 = fmaf(hv[3], w3[1], y1);
            y2 = fmaf(hv[3], w3[2], y2); y3 = fmaf(hv[3], w3[3], y3);
        }
        float ss = y0 * y0 + y1 * y1 + y2 * y2 + y3 * y3;
        ss = dppadd<DPP_QX1>(ss);
        ss = dppadd<DPP_QX2>(ss);
        ss = dppadd<DPP_RR4>(ss);
        ss = dppadd<DPP_RR8>(ss);
        float rn = 1.f / fmaxf(sqrtf(ss), 1e-12f);
        ycn[0] = y0 * rn; ycn[1] = y1 * rn; ycn[2] = y2 * rn; ycn[3] = y3 * rn;
    }

    long ngroups = (Nd + 15) >> 4;
    for (long it = blockIdx.x; it < ngroups; it += gridDim.x) {
        long idx = it * 16 + grp;
        if (idx >= Nd) continue;
        int d = order[idx];
        unsigned beg = rp[d], end = rp[d + 1];
        if (beg == end) {                     // deg-0 fast path (uniform waves)
            *(f32x4*)(outp + (size_t)d * 64 + g * 4) = ycn;
            continue;
        }
        const short* grow = (const short*)gr + (size_t)d * 256 + eoff;
        short8 gr0 = *(const short8*)grow;
        short8 gr1 = *(const short8*)(grow + 8);
        float grf[16];
        cvt16(gr0, gr1, grf);

        float den = 0.f;
        float acc[16];
#pragma unroll
        for (int j = 0; j < 16; ++j) acc[j] = 0.f;

        unsigned e = beg;
        if ((end - beg) & 1u) {               // odd peel
            int si = ssrc[e];
            const short* p0 = (const short*)gl + (size_t)si * 256 + eoff;
            short8 gA = *(const short8*)p0;
            short8 gB = *(const short8*)(p0 + 8);
            float glf[16];
            cvt16(gA, gB, glf);
            float pd = 0.f;
#pragma unroll
            for (int j = 0; j < 16; ++j) {
                float v = glf[j] + grf[j];
                pd = fmaf(fmaxf(v, 0.2f * v), at[j], pd);
            }
            pd = dppadd<DPP_RR4>(pd);
            pd = dppadd<DPP_RR8>(pd);
            float w = __expf(pd);
            den += w;
#pragma unroll
            for (int j = 0; j < 16; ++j) acc[j] = fmaf(w, glf[j], acc[j]);
            ++e;
        }
        for (; e < end; e += 2) {             // pairs: 2-way ILP
            int s0 = ssrc[e], s1 = ssrc[e + 1];
            const short* p0 = (const short*)gl + (size_t)s0 * 256 + eoff;
            const short* p1 = (const short*)gl + (size_t)s1 * 256 + eoff;
            short8 a0 = *(const short8*)p0;
            short8 b0 = *(const short8*)(p0 + 8);
            short8 a1 = *(const short8*)p1;
            short8 b1 = *(const short8*)(p1 + 8);
            float f0[16], f1[16];
            cvt16(a0, b0, f0);
            cvt16(a1, b1, f1);
            float pd0 = 0.f, pd1 = 0.f;
#pragma unroll
            for (int j = 0; j < 16; ++j) {
                float v0 = f0[j] + grf[j];
                pd0 = fmaf(fmaxf(v0, 0.2f * v0), at[j], pd0);
                float v1 = f1[j] + grf[j];
                pd1 = fmaf(fmaxf(v1, 0.2f * v1), at[j], pd1);
            }
            pd0 = dppadd<DPP_RR4>(pd0);
            pd0 = dppadd<DPP_RR8>(pd0);
            pd1 = dppadd<DPP_RR4>(pd1);
            pd1 = dppadd<DPP_RR8>(pd1);
            float w0 = __expf(pd0), w1 = __expf(pd1);
            den += w0 + w1;
#pragma unroll
            for (int j = 0; j < 16; ++j)
                acc[j] = fmaf(w1, f1[j], fmaf(w0, f0[j], acc[j]));
        }
        float inv = 1.f / den;

        float x[16];
#pragma unroll
        for (int j = 0; j < 16; ++j) {
            float v = acc[j] * inv;
            v = dppadd<DPP_QX1>(v);       // sum over 4 heads (quad)
            v = dppadd<DPP_QX2>(v);
            x[j] = v;
        }
#pragma unroll
        for (int j = 0; j < 16; ++j) {
            float v = fmaf(0.25f, x[j], bL[q * 16 + j]);
            x[j] = v > 0.f ? v : (__expf(v) - 1.f);
        }
        if (h == 0) {
#pragma unroll
            for (int j = 0; j < 16; ++j) hL[grp][q * 16 + j] = x[j];
        }
        __builtin_amdgcn_wave_barrier();   // same-wave LDS producer/consumer

        float y0 = lbv[0], y1 = lbv[1], y2 = lbv[2], y3 = lbv[3];
#pragma unroll
        for (int c = 0; c < 64; c += 4) {
            f32x4 hv = *(const f32x4*)&hL[grp][c];          // broadcast
            const float* wr = WL + c * 64 + g * 4;
            f32x4 w0 = *(const f32x4*)(wr);
            f32x4 w1 = *(const f32x4*)(wr + 64);
            f32x4 w2 = *(const f32x4*)(wr + 128);
            f32x4 w3 = *(const f32x4*)(wr + 192);
            y0 = fmaf(hv[0], w0[0], y0); y1 = fmaf(hv[0], w0[1], y1);
            y2 = fmaf(hv[0], w0[2], y2); y3 = fmaf(hv[0], w0[3], y3);
            y0 = fmaf(hv[1], w1[0], y0); y1 = fmaf(hv[1], w1[1], y1);
            y2 = fmaf(hv[1], w1[2], y2); y3 = fmaf(hv[1], w1[3], y3);
            y0 = fmaf(hv[2], w2[0], y0); y1 = fmaf(hv[2], w2[1], y1);
            y2 = fmaf(hv[2], w2[2], y2); y3 = fmaf(hv[2], w2[3], y3);
            y0 = fmaf(hv[3], w3[0], y0); y1 = fmaf(hv[3], w3[1], y1);
            y2 = fmaf(hv[3], w3[2], y2); y3 = fmaf(hv[3], w3[3], y3);
        }
        float ss = y0 * y0 + y1 * y1 + y2 * y2 + y3 * y3;
        ss = dppadd<DPP_QX1>(ss);
        ss = dppadd<DPP_QX2>(ss);
        ss = dppadd<DPP_RR4>(ss);
        ss = dppadd<DPP_RR8>(ss);
        float rn = 1.f / fmaxf(sqrtf(ss), 1e-12f);
        f32x4 yo = {y0 * rn, y1 * rn, y2 * rn, y3 * rn};
        *(f32x4*)(outp + (size_t)d * 64 + g * 4) = yo;
    }
}

// ---------------------------------------------------------------------------
// gat_b: fused GATv2 (genre phase). One block per dst; 16 lane-groups stride
// edges with prefetch; no-max softmax => partial merge is a plain sum via LDS.
// Epilogue fuses elu + 64x64 linear + l2norm + store (genre tail).
// ---------------------------------------------------------------------------
__global__ __launch_bounds__(256) void gat_b(
    const bf16* __restrict__ gl, const bf16* __restrict__ gr,
    const int* __restrict__ ssrc, const unsigned* __restrict__ rp,
    const float* __restrict__ att, const float* __restrict__ bias,
    const float* __restrict__ linW, const float* __restrict__ linb,
    float* __restrict__ outp, int Nd)
{
    __shared__ float accL[16][256];
    __shared__ float denL[16][4];
    int grp = threadIdx.x >> 4, g = threadIdx.x & 15;
    int h = g & 3, q = g >> 2;
    int eoff = h * 64 + q * 16;
    int d = blockIdx.x;

    float at[16];
#pragma unroll
    for (int j = 0; j < 16; ++j) at[j] = att[eoff + j];

    const short* grow = (const short*)gr + (size_t)d * 256 + eoff;
    short8 gr0 = *(const short8*)grow;
    short8 gr1 = *(const short8*)(grow + 8);
    float grf[16];
    cvt16(gr0, gr1, grf);

    unsigned beg = rp[d], end = rp[d + 1];
    float den = 0.f;
    float acc[16];
#pragma unroll
    for (int j = 0; j < 16; ++j) acc[j] = 0.f;

    unsigned e = beg + grp;
    if (e < end) {
        int si = ssrc[e];
        const short* p0 = (const short*)gl + (size_t)si * 256 + eoff;
        short8 gA = *(const short8*)p0;
        short8 gB = *(const short8*)(p0 + 8);
        while (true) {
            float glf[16];
            cvt16(gA, gB, glf);
            e += 16;
            bool more = e < end;
            if (more) {
                int s2 = ssrc[e];
                const short* p2 = (const short*)gl + (size_t)s2 * 256 + eoff;
                gA = *(const short8*)p2;
                gB = *(const short8*)(p2 + 8);
            }
            float pd = 0.f;
#pragma unroll
            for (int j = 0; j < 16; ++j) {
                float v = glf[j] + grf[j];
                float lr = fmaxf(v, 0.2f * v);
                pd = fmaf(lr, at[j], pd);
            }
            pd = dppadd<DPP_RR4>(pd);
            pd = dppadd<DPP_RR8>(pd);
            float w = __expf(pd);
            den += w;
#pragma unroll
            for (int j = 0; j < 16; ++j) acc[j] = fmaf(w, glf[j], acc[j]);
            if (!more) break;
        }
    }
#pragma unroll
    for (int j = 0; j < 16; ++j) accL[grp][eoff + j] = acc[j];
    if (q == 0) denL[grp][h] = den;
    __syncthreads();

    int t = threadIdx.x;
    int hh = t >> 6, cc = t & 63;
    float sa = 0.f, sd = 0.f;
#pragma unroll
    for (int k = 0; k < 16; ++k) { sa += accL[k][hh * 64 + cc]; sd += denL[k][hh]; }
    float xv = sd > 0.f ? sa / sd : 0.f;
    __syncthreads();
    accL[0][t] = xv;
    __syncthreads();
    if (t < 64) {
        float m4 = 0.25f * (accL[0][t] + accL[0][64 + t] + accL[0][128 + t] + accL[0][192 + t]);
        float v = m4 + bias[t];
        accL[1][t] = v > 0.f ? v : (__expf(v) - 1.f);
    }
    __syncthreads();
    if (t < 64) {
        float y = linb[t];
        for (int c = 0; c < 64; ++c) y = fmaf(accL[1][c], linW[c * 64 + t], y);
        float ss = y * y;
        ss += __shfl_xor(ss, 1);  ss += __shfl_xor(ss, 2);  ss += __shfl_xor(ss, 4);
        ss += __shfl_xor(ss, 8);  ss += __shfl_xor(ss, 16); ss += __shfl_xor(ss, 32);
        float rn = 1.f / fmaxf(sqrtf(ss), 1e-12f);
        outp[(size_t)d * 64 + t] = y * rn;
    }
}

// ---------------------------------------------------------------------------

static inline unsigned gridFor(long n) { return (unsigned)((n + 255) / 256); }

extern "C" void kernel_launch(void* const* d_in, const int* in_sizes, int n_in,
                              void* d_out, int out_size, void* d_ws, size_t ws_size,
                              hipStream_t stream) {
    const float* x_artist = (const float*)d_in[0];
    const float* x_track  = (const float*)d_in[1];
    const float* x_genre  = (const float*)d_in[2];
    const float* enc_Wa = (const float*)d_in[3];  const float* enc_ba = (const float*)d_in[4];
    const float* enc_Wt = (const float*)d_in[5];  const float* enc_bt = (const float*)d_in[6];
    const float* enc_Wg = (const float*)d_in[7];  const float* enc_bg = (const float*)d_in[8];
    const int* src_pt = (const int*)d_in[9];
    const int* dst_pt = (const int*)d_in[10];
    const int* src_tg = (const int*)d_in[11];
    const int* dst_tg = (const int*)d_in[12];
    // layer l=1 slices (hidden never fed back -> only last layer matters)
    const float* Wl_pt   = (const float*)d_in[13] + 64 * 256;
    const float* bl_pt   = (const float*)d_in[14] + 256;
    const float* Wr_pt   = (const float*)d_in[15] + 64 * 256;
    const float* br_pt   = (const float*)d_in[16] + 256;
    const float* att_pt  = (const float*)d_in[17] + 256;
    const float* bias_pt = (const float*)d_in[18] + 64;
    const float* Wl_tg   = (const float*)d_in[19] + 64 * 256;
    const float* bl_tg   = (const float*)d_in[20] + 256;
    const float* Wr_tg   = (const float*)d_in[21] + 64 * 256;
    const float* br_tg   = (const float*)d_in[22] + 256;
    const float* att_tg  = (const float*)d_in[23] + 256;
    const float* bias_tg = (const float*)d_in[24] + 64;
    const float* lin_track_W = (const float*)d_in[25];
    const float* lin_track_b = (const float*)d_in[26];
    const float* lin_genre_W = (const float*)d_in[27];
    const float* lin_genre_b = (const float*)d_in[28];

    float* out = (float*)d_out;

    const int NTOT = NT + NG;

    // ---- workspace layout (~216 MB) ----
    char* p = (char*)d_ws;
    auto take = [&](size_t bytes) { char* q = p; p += (bytes + 255) & ~(size_t)255; return q; };
    char* region = take((size_t)NA * 256 * 2 + (size_t)NT * 256 * 2);   // 204.8 MB
    bf16*  gl_pt  = (bf16*)region;                                      // pt: [0, 51.2 MB)
    bf16*  gr_pt  = (bf16*)(region + (size_t)NA * 256 * 2);             // pt: [51.2, 204.8)
    bf16*  gl_tg  = (bf16*)region;                                      // tg: [0, 153.6)
    unsigned* counts = (unsigned*)take((size_t)(NTOT + 1) * 4);
    unsigned* rowptr = (unsigned*)take((size_t)(NTOT + 1) * 4);
    unsigned* cursor = (unsigned*)take((size_t)NTOT * 4);
    unsigned* part   = (unsigned*)take((size_t)2048 * 4);
    int*      ssrc   = (int*)take((size_t)(EPT + ETG) * 4);
    int*      order  = (int*)take((size_t)NT * 4);
    unsigned* bcnt   = (unsigned*)take((size_t)DBK * DSB * 4);
    unsigned* bbase  = (unsigned*)take((size_t)DBK * DSB * 4);
    bf16*     gr_tg  = (bf16*)take((size_t)NG * 256 * 2);               // 1 MB
    short*    Bf     = (short*)take((size_t)(64 + 96 + 96 + 32) * 256 * 2);
    float*    bc     = (float*)take((size_t)4 * 256 * 4);

    short* BfGLpt = Bf;                       // K=64
    short* BfGRpt = BfGLpt + 64 * 256;        // K=96
    short* BfGLtg = BfGRpt + 96 * 256;        // K=96
    short* BfGRtg = BfGLtg + 96 * 256;        // K=32
    float* bcGLpt = bc;
    float* bcGRpt = bc + 256;
    float* bcGLtg = bc + 512;
    float* bcGRtg = bc + 768;

    dim3 blk(256);

    // ---- fold encoders into GAT transforms (fused combine+convert+bias) ----
    wprep<<<8,  blk, 0, stream>>>(enc_Wa, Wl_pt, bl_pt, enc_ba, BfGLpt, bcGLpt, 2);
    wprep<<<12, blk, 0, stream>>>(enc_Wt, Wr_pt, br_pt, enc_bt, BfGRpt, bcGRpt, 3);
    wprep<<<12, blk, 0, stream>>>(enc_Wt, Wl_tg, bl_tg, enc_bt, BfGLtg, bcGLtg, 3);
    wprep<<<4,  blk, 0, stream>>>(enc_Wg, Wr_tg, br_tg, enc_bg, BfGRtg, bcGRtg, 1);

    // ---- merged counting sort: concatenated CSR over [pt dsts | tg dsts] ----
    {
        int n = NTOT + 1;
        unsigned sgrid = (unsigned)((n + 1023) / 1024);
        fill_u32<<<gridFor(n), blk, 0, stream>>>(counts, 0u, n);
        histo<<<gridFor(EPT), blk, 0, stream>>>(dst_pt, counts, 0, EPT);
        histo<<<gridFor(ETG), blk, 0, stream>>>(dst_tg, counts, NT, ETG);
        scan_a<<<sgrid, blk, 0, stream>>>(counts, rowptr, part, n);
        scan_a<<<1, blk, 0, stream>>>(part, part, part + 1536, (int)sgrid);
        scan_c<<<gridFor(n), blk, 0, stream>>>(rowptr, part, cursor, n);
        scat<<<gridFor(EPT), blk, 0, stream>>>(src_pt, dst_pt, cursor, 0, ssrc, EPT);
        scat<<<gridFor(ETG), blk, 0, stream>>>(src_tg, dst_tg, cursor, NT, ssrc, ETG);
    }

    // ---- degree-sort pt dsts (contention-free: LDS histograms) ----
    deg_cnt  <<<DSB, blk, 0, stream>>>(rowptr, bcnt, NT);
    scan4k   <<<1,   blk, 0, stream>>>(bcnt, bbase);
    deg_place<<<DSB, blk, 0, stream>>>(rowptr, bbase, order, NT);

    // ================= performed: artist -> track =================
    tformf<2><<<(NA + 63) / 64, blk, 0, stream>>>(x_artist, BfGLpt, bcGLpt, gl_pt, NA);
    tformf<3><<<(NT + 63) / 64, blk, 0, stream>>>(x_track,  BfGRpt, bcGRpt, gr_pt, NT);

    gat_w<<<2048, blk, 0, stream>>>(gl_pt, gr_pt, ssrc, rowptr, order, att_pt, bias_pt,
                                    lin_track_W, lin_track_b, out, NT);

    // ================= has_genre: track -> genre =================
    tformf<3><<<(NT + 63) / 64, blk, 0, stream>>>(x_track, BfGLtg, bcGLtg, gl_tg, NT);
    tformf<1><<<(NG + 63) / 64, blk, 0, stream>>>(x_genre, BfGRtg, bcGRtg, gr_tg, NG);

    gat_b<<<NG, blk, 0, stream>>>(gl_tg, gr_tg, ssrc, rowptr + NT, att_tg, bias_tg,
                                  lin_genre_W, lin_genre_b, out + (size_t)NT * 64, NG);
}

// Round 8
// 779.425 us; speedup vs baseline: 1.2805x; 1.2805x over previous
//
#include <hip/hip_runtime.h>
#include <hip/hip_bf16.h>

typedef __hip_bfloat16 bf16;
typedef __attribute__((ext_vector_type(8))) short short8;   // 8 bf16 (4 VGPRs)
typedef __attribute__((ext_vector_type(4))) float f32x4;

#define NA 100000
#define NT 300000
#define NG 2000
#define EPT 600000
#define ETG 400000

#define DSB 64   // degree-sort blocks
#define DBK 64   // degree buckets (deg capped at DBK-1)
#define LOG2E 1.44269504088896f

// DPP control codes
#define DPP_QX1 0xB1   // quad_perm [1,0,3,2]  (xor 1)
#define DPP_QX2 0x4E   // quad_perm [2,3,0,1]  (xor 2)
#define DPP_RR4 0x124  // row_ror:4
#define DPP_RR8 0x128  // row_ror:8

template <int CTRL>
__device__ __forceinline__ float dppadd(float x) {
    int y = __builtin_amdgcn_update_dpp(0, __float_as_int(x), CTRL, 0xf, 0xf, true);
    return x + __int_as_float(y);
}

__device__ __forceinline__ float b2f(short s) {
    return __uint_as_float(((unsigned)(unsigned short)s) << 16);
}
__device__ __forceinline__ void cvt16(short8 a, short8 b, float* f) {
#pragma unroll
    for (int j = 0; j < 8; ++j) f[j] = b2f(a[j]);
#pragma unroll
    for (int j = 0; j < 8; ++j) f[8 + j] = b2f(b[j]);
}
__device__ __forceinline__ short f2bs(float x) {
    return (short)__builtin_bit_cast(unsigned short, __float2bfloat16(x));
}

__global__ void fill_u32(unsigned* __restrict__ p, unsigned v, long n) {
    long i = (long)blockIdx.x * 256 + threadIdx.x;
    if (i < n) p[i] = v;
}

// ---------------------------------------------------------------------------
// wprep_all: all four fused (We@Wl)->bf16-fragment weight preps in ONE launch.
// Frag order: idx = (((ks*16+nt)*4+kb)*16+c)*8+j holds Wc[(ks*32+kb*8+j)*256+nt*16+c]
// Block ranges: [0,8) p0(KS2), [8,20) p1(KS3), [20,32) p2(KS3), [32,36) p3(KS1).
// First block of each range also computes bc[256] = be@Wl + bl.
// ---------------------------------------------------------------------------
struct WP { const float *We, *Wl, *bl, *be; short* Bf; float* bc; int KS, b0; };

__global__ __launch_bounds__(256) void wprep_all(WP p0, WP p1, WP p2, WP p3) {
    int b = blockIdx.x;
    WP p;
    if (b < 8) p = p0; else if (b < 20) p = p1; else if (b < 32) p = p2; else p = p3;
    int lb = b - p.b0;
    int t = lb * 256 + threadIdx.x;
    if (t < p.KS * 1024) {
        int c = t & 15, kb = (t >> 4) & 3, nt = (t >> 6) & 15, ks = t >> 10;
        int k0 = ks * 32 + kb * 8, n = nt * 16 + c;
        short8 o;
#pragma unroll
        for (int j = 0; j < 8; ++j) {
            int k = k0 + j;
            float acc = 0.f;
            for (int cc = 0; cc < 64; ++cc)
                acc = fmaf(p.We[k * 64 + cc], p.Wl[cc * 256 + n], acc);
            o[j] = f2bs(acc);
        }
        ((short8*)p.Bf)[t] = o;
    }
    if (lb == 0) {
        int j = threadIdx.x;
        float acc = p.bl[j];
        for (int cc = 0; cc < 64; ++cc) acc = fmaf(p.be[cc], p.Wl[cc * 256 + j], acc);
        p.bc[j] = acc;
    }
}

// ---------------------------------------------------------------------------
// tformf: C[M x 256] = bf16(A[M x K] f32) @ B (bf16 frag-ordered) + bias, MFMA.
// (R6-proven store pattern: 64 scalar bf16 stores, dense 32B segments/wave.)
// ---------------------------------------------------------------------------
template <int KS>
__global__ __launch_bounds__(256) void tformf(
    const float* __restrict__ A, const short* __restrict__ Bf,
    const float* __restrict__ bias, bf16* __restrict__ C, int M)
{
    constexpr int K = KS * 32;
    int wv = threadIdx.x >> 6, lane = threadIdx.x & 63;
    int lrow = lane & 15, kb = lane >> 4;
    int base = blockIdx.x * 64 + wv * 16;

    int arow = base + lrow; if (arow >= M) arow = M - 1;
    const float* Ap = A + (size_t)arow * K + kb * 8;
    short8 a[KS];
#pragma unroll
    for (int s = 0; s < KS; ++s) {
        f32x4 lo = *(const f32x4*)(Ap + s * 32);
        f32x4 hi = *(const f32x4*)(Ap + s * 32 + 4);
#pragma unroll
        for (int j = 0; j < 4; ++j) {
            a[s][j]     = f2bs(lo[j]);
            a[s][4 + j] = f2bs(hi[j]);
        }
    }

    const short8* Bl = (const short8*)Bf + kb * 16 + lrow;

    f32x4 acc[16];
#pragma unroll
    for (int nt = 0; nt < 16; ++nt) {
        float bv = bias[nt * 16 + lrow];
        f32x4 bvv = {bv, bv, bv, bv};
        acc[nt] = bvv;
    }
#pragma unroll
    for (int nt = 0; nt < 16; ++nt) {
#pragma unroll
        for (int s = 0; s < KS; ++s)
            acc[nt] = __builtin_amdgcn_mfma_f32_16x16x32_bf16(
                a[s], Bl[(s * 16 + nt) * 64], acc[nt], 0, 0, 0);
    }
    int r0 = base + kb * 4;
#pragma unroll
    for (int nt = 0; nt < 16; ++nt) {
#pragma unroll
        for (int r = 0; r < 4; ++r) {
            int row = r0 + r;
            if (row < M)
                C[(size_t)row * 256 + nt * 16 + lrow] = __float2bfloat16(acc[nt][r]);
        }
    }
}

// ---------------------------------------------------------------------------
// tformf2: TWO transforms of the same A (x_track, K=96) in one pass —
// A loaded & converted once, two MFMA passes, two outputs. Requires C1, C2
// to be live simultaneously (non-aliased workspace).
// ---------------------------------------------------------------------------
__global__ __launch_bounds__(256) void tformf2(
    const float* __restrict__ A,
    const short* __restrict__ Bf1, const float* __restrict__ b1, bf16* __restrict__ C1,
    const short* __restrict__ Bf2, const float* __restrict__ b2, bf16* __restrict__ C2,
    int M)
{
    constexpr int KS = 3, K = 96;
    int wv = threadIdx.x >> 6, lane = threadIdx.x & 63;
    int lrow = lane & 15, kb = lane >> 4;
    int base = blockIdx.x * 64 + wv * 16;

    int arow = base + lrow; if (arow >= M) arow = M - 1;
    const float* Ap = A + (size_t)arow * K + kb * 8;
    short8 a[KS];
#pragma unroll
    for (int s = 0; s < KS; ++s) {
        f32x4 lo = *(const f32x4*)(Ap + s * 32);
        f32x4 hi = *(const f32x4*)(Ap + s * 32 + 4);
#pragma unroll
        for (int j = 0; j < 4; ++j) {
            a[s][j]     = f2bs(lo[j]);
            a[s][4 + j] = f2bs(hi[j]);
        }
    }
    int r0 = base + kb * 4;

    const short8* Bl1 = (const short8*)Bf1 + kb * 16 + lrow;
    f32x4 acc[16];
#pragma unroll
    for (int nt = 0; nt < 16; ++nt) {
        float bv = b1[nt * 16 + lrow];
        f32x4 bvv = {bv, bv, bv, bv};
        acc[nt] = bvv;
    }
#pragma unroll
    for (int nt = 0; nt < 16; ++nt) {
#pragma unroll
        for (int s = 0; s < KS; ++s)
            acc[nt] = __builtin_amdgcn_mfma_f32_16x16x32_bf16(
                a[s], Bl1[(s * 16 + nt) * 64], acc[nt], 0, 0, 0);
    }
#pragma unroll
    for (int nt = 0; nt < 16; ++nt) {
#pragma unroll
        for (int r = 0; r < 4; ++r) {
            int row = r0 + r;
            if (row < M)
                C1[(size_t)row * 256 + nt * 16 + lrow] = __float2bfloat16(acc[nt][r]);
        }
    }

    const short8* Bl2 = (const short8*)Bf2 + kb * 16 + lrow;
#pragma unroll
    for (int nt = 0; nt < 16; ++nt) {
        float bv = b2[nt * 16 + lrow];
        f32x4 bvv = {bv, bv, bv, bv};
        acc[nt] = bvv;
    }
#pragma unroll
    for (int nt = 0; nt < 16; ++nt) {
#pragma unroll
        for (int s = 0; s < KS; ++s)
            acc[nt] = __builtin_amdgcn_mfma_f32_16x16x32_bf16(
                a[s], Bl2[(s * 16 + nt) * 64], acc[nt], 0, 0, 0);
    }
#pragma unroll
    for (int nt = 0; nt < 16; ++nt) {
#pragma unroll
        for (int r = 0; r < 4; ++r) {
            int row = r0 + r;
            if (row < M)
                C2[(size_t)row * 256 + nt * 16 + lrow] = __float2bfloat16(acc[nt][r]);
        }
    }
}

// ============================ edge sort (CSR by dst) ========================
// merged over [pt edges | tg edges]
__global__ __launch_bounds__(256) void histo_all(
    const int* __restrict__ dpt, const int* __restrict__ dtg,
    unsigned* __restrict__ cnt)
{
    int i = blockIdx.x * 256 + threadIdx.x;
    if (i < EPT) atomicAdd(&cnt[dpt[i]], 1u);
    else if (i < EPT + ETG) atomicAdd(&cnt[NT + dtg[i - EPT]], 1u);
}

__global__ __launch_bounds__(256) void scat_all(
    const int* __restrict__ spt, const int* __restrict__ dpt,
    const int* __restrict__ stg, const int* __restrict__ dtg,
    unsigned* __restrict__ cur, int* __restrict__ ss)
{
    int i = blockIdx.x * 256 + threadIdx.x;
    if (i < EPT) {
        unsigned p = atomicAdd(&cur[dpt[i]], 1u);
        ss[p] = spt[i];
    } else if (i < EPT + ETG) {
        unsigned p = atomicAdd(&cur[NT + dtg[i - EPT]], 1u);
        ss[p] = stg[i - EPT];
    }
}

__global__ __launch_bounds__(256) void scan_a(
    const unsigned* __restrict__ in, unsigned* __restrict__ out,
    unsigned* __restrict__ part, int n)
{
    __shared__ unsigned ts[256];
    int t = threadIdx.x;
    long base = (long)blockIdx.x * 1024 + (long)t * 4;
    unsigned v0 = 0, v1 = 0, v2 = 0, v3 = 0;
    if (base + 0 < n) v0 = in[base + 0];
    if (base + 1 < n) v1 = in[base + 1];
    if (base + 2 < n) v2 = in[base + 2];
    if (base + 3 < n) v3 = in[base + 3];
    unsigned s = v0 + v1 + v2 + v3;
    ts[t] = s;
    __syncthreads();
    unsigned run = s;
    for (int off = 1; off < 256; off <<= 1) {
        unsigned y = (t >= off) ? ts[t - off] : 0u;
        __syncthreads();
        run += y; ts[t] = run;
        __syncthreads();
    }
    unsigned ex = run - s;
    if (base + 0 < n) out[base + 0] = ex;
    if (base + 1 < n) out[base + 1] = ex + v0;
    if (base + 2 < n) out[base + 2] = ex + v0 + v1;
    if (base + 3 < n) out[base + 3] = ex + v0 + v1 + v2;
    if (t == 255) part[blockIdx.x] = run;
}

__global__ __launch_bounds__(256) void scan_c(
    unsigned* __restrict__ rp, const unsigned* __restrict__ part,
    unsigned* __restrict__ cur, int n)
{
    long i = (long)blockIdx.x * 256 + threadIdx.x;
    if (i >= n) return;
    unsigned v = rp[i] + part[i >> 10];
    rp[i] = v;
    if (i < n - 1) cur[i] = v;
}

// ======== contention-free degree sort (pt dsts -> order[]) ========
__global__ __launch_bounds__(256) void deg_cnt(
    const unsigned* __restrict__ rp, unsigned* __restrict__ bcnt, int n)
{
    __shared__ unsigned hcnt[DBK];
    int b = blockIdx.x;
    int chunk = (n + DSB - 1) / DSB;
    int lo = b * chunk, hi = min(n, lo + chunk);
    if (threadIdx.x < DBK) hcnt[threadIdx.x] = 0u;
    __syncthreads();
    for (int i = lo + threadIdx.x; i < hi; i += 256) {
        unsigned deg = rp[i + 1] - rp[i];
        if (deg > DBK - 1) deg = DBK - 1;
        atomicAdd(&hcnt[deg], 1u);          // LDS atomic: intra-block only
    }
    __syncthreads();
    if (threadIdx.x < DBK) bcnt[(size_t)threadIdx.x * DSB + b] = hcnt[threadIdx.x];
}

__global__ __launch_bounds__(256) void scan4k(
    const unsigned* __restrict__ in, unsigned* __restrict__ out)
{
    __shared__ unsigned ts[256];
    int t = threadIdx.x;
    unsigned v[16]; unsigned s = 0;
#pragma unroll
    for (int j = 0; j < 16; ++j) { v[j] = in[t * 16 + j]; s += v[j]; }
    ts[t] = s;
    __syncthreads();
    unsigned run = s;
    for (int off = 1; off < 256; off <<= 1) {
        unsigned y = (t >= off) ? ts[t - off] : 0u;
        __syncthreads();
        run += y; ts[t] = run;
        __syncthreads();
    }
    unsigned ex = run - s;
#pragma unroll
    for (int j = 0; j < 16; ++j) { out[t * 16 + j] = ex; ex += v[j]; }
}

__global__ __launch_bounds__(256) void deg_place(
    const unsigned* __restrict__ rp, const unsigned* __restrict__ base,
    int* __restrict__ order, int n)
{
    __shared__ unsigned hcur[DBK];
    int b = blockIdx.x;
    int chunk = (n + DSB - 1) / DSB;
    int lo = b * chunk, hi = min(n, lo + chunk);
    if (threadIdx.x < DBK) hcur[threadIdx.x] = base[(size_t)threadIdx.x * DSB + b];
    __syncthreads();
    for (int i = lo + threadIdx.x; i < hi; i += 256) {
        unsigned deg = rp[i + 1] - rp[i];
        if (deg > DBK - 1) deg = DBK - 1;
        unsigned p = atomicAdd(&hcur[deg], 1u);   // LDS atomic
        order[p] = i;
    }
}

// ---------------------------------------------------------------------------
// gat_w: fused GATv2 (track phase), 16-lane-group per dst (4 dst per wave),
// degree-sorted order; deg-0 fast path; 1-deep gl prefetch (R6-proven loop).
// att pre-scaled by log2e -> logits exp via bare v_exp (exp2f).
// Epilogue fuses bias+elu+64x64 linear+l2norm+store.
// ---------------------------------------------------------------------------
__global__ __launch_bounds__(256) void gat_w(
    const bf16* __restrict__ gl, const bf16* __restrict__ gr,
    const int* __restrict__ ssrc, const unsigned* __restrict__ rp,
    const int* __restrict__ order,
    const float* __restrict__ att, const float* __restrict__ bias,
    const float* __restrict__ linW, const float* __restrict__ linb,
    float* __restrict__ outp, int Nd)
{
    __shared__ float WL[4096];        // linW [c][j] row-major
    __shared__ float bL[64];
    __shared__ float hC[64];          // deg-0 constant h
    __shared__ float hL[16][68];      // per-group h, padded
    for (int t = threadIdx.x; t < 4096; t += 256) WL[t] = linW[t];
    if (threadIdx.x < 64) {
        float b = bias[threadIdx.x];
        bL[threadIdx.x] = b;
        hC[threadIdx.x] = b > 0.f ? b : (__expf(b) - 1.f);
    }
    __syncthreads();

    int grp = threadIdx.x >> 4, g = threadIdx.x & 15;
    int h = g & 3, q = g >> 2;
    int eoff = h * 64 + q * 16;

    float at[16];
#pragma unroll
    for (int j = 0; j < 16; ++j) at[j] = att[eoff + j] * LOG2E;
    f32x4 lbv = *(const f32x4*)(linb + g * 4);

    // ---- precompute deg-0 constant output (normalized) ----
    f32x4 ycn;
    {
        float y0 = lbv[0], y1 = lbv[1], y2 = lbv[2], y3 = lbv[3];
#pragma unroll
        for (int c = 0; c < 64; c += 4) {
            f32x4 hv = *(const f32x4*)&hC[c];
            const float* wr = WL + c * 64 + g * 4;
            f32x4 w0 = *(const f32x4*)(wr);
            f32x4 w1 = *(const f32x4*)(wr + 64);
            f32x4 w2 = *(const f32x4*)(wr + 128);
            f32x4 w3 = *(const f32x4*)(wr + 192);
            y0 = fmaf(hv[0], w0[0], y0); y1 = fmaf(hv[0], w0[1], y1);
            y2 = fmaf(hv[0], w0[2], y2); y3 = fmaf(hv[0], w0[3], y3);
            y0 = fmaf(hv[1], w1[0], y0); y1 = fmaf(hv[1], w1[1], y1);
            y2 = fmaf(hv[1], w1[2], y2); y3 = fmaf(hv[1], w1[3], y3);
            y0 = fmaf(hv[2], w2[0], y0); y1 = fmaf(hv[2], w2[1], y1);
            y2 = fmaf(hv[2], w2[2], y2); y3 = fmaf(hv[2], w2[3], y3);
            y0 = fmaf(hv[3], w3[0], y0); y1 = fmaf(hv[3], w3[1], y1);
            y2 = fmaf(hv[3], w3[2], y2); y3 = fmaf(hv[3], w3[3], y3);
        }
        float ss = y0 * y0 + y1 * y1 + y2 * y2 + y3 * y3;
        ss = dppadd<DPP_QX1>(ss);
        ss = dppadd<DPP_QX2>(ss);
        ss = dppadd<DPP_RR4>(ss);
        ss = dppadd<DPP_RR8>(ss);
        float rn = 1.f / fmaxf(sqrtf(ss), 1e-12f);
        ycn[0] = y0 * rn; ycn[1] = y1 * rn; ycn[2] = y2 * rn; ycn[3] = y3 * rn;
    }

    long ngroups = (Nd + 15) >> 4;
    for (long it = blockIdx.x; it < ngroups; it += gridDim.x) {
        long idx = it * 16 + grp;
        if (idx >= Nd) continue;
        int d = order[idx];
        unsigned beg = rp[d], end = rp[d + 1];
        if (beg == end) {                     // deg-0 fast path (uniform waves)
            *(f32x4*)(outp + (size_t)d * 64 + g * 4) = ycn;
            continue;
        }
        const short* grow = (const short*)gr + (size_t)d * 256 + eoff;
        short8 gr0 = *(const short8*)grow;
        short8 gr1 = *(const short8*)(grow + 8);
        float grf[16];
        cvt16(gr0, gr1, grf);

        float den = 0.f;
        float acc[16];
#pragma unroll
        for (int j = 0; j < 16; ++j) acc[j] = 0.f;

        // software-pipelined edge loop (prefetch next gl row)
        unsigned e = beg;
        {
            int si = ssrc[e];
            const short* p0 = (const short*)gl + (size_t)si * 256 + eoff;
            short8 gA = *(const short8*)p0;
            short8 gB = *(const short8*)(p0 + 8);
            while (true) {
                float glf[16];
                cvt16(gA, gB, glf);
                ++e;
                bool more = e < end;
                if (more) {
                    int s2 = ssrc[e];
                    const short* p2 = (const short*)gl + (size_t)s2 * 256 + eoff;
                    gA = *(const short8*)p2;
                    gB = *(const short8*)(p2 + 8);
                }
                float pd = 0.f;
#pragma unroll
                for (int j = 0; j < 16; ++j) {
                    float v = glf[j] + grf[j];
                    float lr = fmaxf(v, 0.2f * v);
                    pd = fmaf(lr, at[j], pd);
                }
                pd = dppadd<DPP_RR4>(pd);     // sum over same-head lanes
                pd = dppadd<DPP_RR8>(pd);
                float w = exp2f(pd);          // att pre-scaled by log2e
                den += w;
#pragma unroll
                for (int j = 0; j < 16; ++j) acc[j] = fmaf(w, glf[j], acc[j]);
                if (!more) break;
            }
        }
        float inv = 1.f / den;

        float x[16];
#pragma unroll
        for (int j = 0; j < 16; ++j) {
            float v = acc[j] * inv;
            v = dppadd<DPP_QX1>(v);       // sum over 4 heads (quad)
            v = dppadd<DPP_QX2>(v);
            x[j] = v;
        }
#pragma unroll
        for (int j = 0; j < 16; ++j) {
            float v = fmaf(0.25f, x[j], bL[q * 16 + j]);
            x[j] = v > 0.f ? v : (__expf(v) - 1.f);
        }
        if (h == 0) {
#pragma unroll
            for (int j = 0; j < 16; ++j) hL[grp][q * 16 + j] = x[j];
        }
        __builtin_amdgcn_wave_barrier();   // same-wave LDS producer/consumer

        float y0 = lbv[0], y1 = lbv[1], y2 = lbv[2], y3 = lbv[3];
#pragma unroll
        for (int c = 0; c < 64; c += 4) {
            f32x4 hv = *(const f32x4*)&hL[grp][c];          // broadcast
            const float* wr = WL + c * 64 + g * 4;
            f32x4 w0 = *(const f32x4*)(wr);
            f32x4 w1 = *(const f32x4*)(wr + 64);
            f32x4 w2 = *(const f32x4*)(wr + 128);
            f32x4 w3 = *(const f32x4*)(wr + 192);
            y0 = fmaf(hv[0], w0[0], y0); y1 = fmaf(hv[0], w0[1], y1);
            y2 = fmaf(hv[0], w0[2], y2); y3 = fmaf(hv[0], w0[3], y3);
            y0 = fmaf(hv[1], w1[0], y0); y1 = fmaf(hv[1], w1[1], y1);
            y2 = fmaf(hv[1], w1[2], y2); y3 = fmaf(hv[1], w1[3], y3);
            y0 = fmaf(hv[2], w2[0], y0); y1 = fmaf(hv[2], w2[1], y1);
            y2 = fmaf(hv[2], w2[2], y2); y3 = fmaf(hv[2], w2[3], y3);
            y0 = fmaf(hv[3], w3[0], y0); y1 = fmaf(hv[3], w3[1], y1);
            y2 = fmaf(hv[3], w3[2], y2); y3 = fmaf(hv[3], w3[3], y3);
        }
        float ss = y0 * y0 + y1 * y1 + y2 * y2 + y3 * y3;
        ss = dppadd<DPP_QX1>(ss);
        ss = dppadd<DPP_QX2>(ss);
        ss = dppadd<DPP_RR4>(ss);
        ss = dppadd<DPP_RR8>(ss);
        float rn = 1.f / fmaxf(sqrtf(ss), 1e-12f);
        f32x4 yo = {y0 * rn, y1 * rn, y2 * rn, y3 * rn};
        *(f32x4*)(outp + (size_t)d * 64 + g * 4) = yo;
    }
}

// ---------------------------------------------------------------------------
// gat_b: fused GATv2 (genre phase). One block per dst; 16 lane-groups stride
// edges with prefetch; no-max softmax => partial merge is a plain sum via LDS.
// Epilogue fuses elu + 64x64 linear + l2norm + store (genre tail).
// ---------------------------------------------------------------------------
__global__ __launch_bounds__(256) void gat_b(
    const bf16* __restrict__ gl, const bf16* __restrict__ gr,
    const int* __restrict__ ssrc, const unsigned* __restrict__ rp,
    const float* __restrict__ att, const float* __restrict__ bias,
    const float* __restrict__ linW, const float* __restrict__ linb,
    float* __restrict__ outp, int Nd)
{
    __shared__ float accL[16][256];
    __shared__ float denL[16][4];
    int grp = threadIdx.x >> 4, g = threadIdx.x & 15;
    int h = g & 3, q = g >> 2;
    int eoff = h * 64 + q * 16;
    int d = blockIdx.x;

    float at[16];
#pragma unroll
    for (int j = 0; j < 16; ++j) at[j] = att[eoff + j] * LOG2E;

    const short* grow = (const short*)gr + (size_t)d * 256 + eoff;
    short8 gr0 = *(const short8*)grow;
    short8 gr1 = *(const short8*)(grow + 8);
    float grf[16];
    cvt16(gr0, gr1, grf);

    unsigned beg = rp[d], end = rp[d + 1];
    float den = 0.f;
    float acc[16];
#pragma unroll
    for (int j = 0; j < 16; ++j) acc[j] = 0.f;

    unsigned e = beg + grp;
    if (e < end) {
        int si = ssrc[e];
        const short* p0 = (const short*)gl + (size_t)si * 256 + eoff;
        short8 gA = *(const short8*)p0;
        short8 gB = *(const short8*)(p0 + 8);
        while (true) {
            float glf[16];
            cvt16(gA, gB, glf);
            e += 16;
            bool more = e < end;
            if (more) {
                int s2 = ssrc[e];
                const short* p2 = (const short*)gl + (size_t)s2 * 256 + eoff;
                gA = *(const short8*)p2;
                gB = *(const short8*)(p2 + 8);
            }
            float pd = 0.f;
#pragma unroll
            for (int j = 0; j < 16; ++j) {
                float v = glf[j] + grf[j];
                float lr = fmaxf(v, 0.2f * v);
                pd = fmaf(lr, at[j], pd);
            }
            pd = dppadd<DPP_RR4>(pd);
            pd = dppadd<DPP_RR8>(pd);
            float w = exp2f(pd);
            den += w;
#pragma unroll
            for (int j = 0; j < 16; ++j) acc[j] = fmaf(w, glf[j], acc[j]);
            if (!more) break;
        }
    }
#pragma unroll
    for (int j = 0; j < 16; ++j) accL[grp][eoff + j] = acc[j];
    if (q == 0) denL[grp][h] = den;
    __syncthreads();

    int t = threadIdx.x;
    int hh = t >> 6, cc = t & 63;
    float sa = 0.f, sd = 0.f;
#pragma unroll
    for (int k = 0; k < 16; ++k) { sa += accL[k][hh * 64 + cc]; sd += denL[k][hh]; }
    float xv = sd > 0.f ? sa / sd : 0.f;
    __syncthreads();
    accL[0][t] = xv;
    __syncthreads();
    if (t < 64) {
        float m4 = 0.25f * (accL[0][t] + accL[0][64 + t] + accL[0][128 + t] + accL[0][192 + t]);
        float v = m4 + bias[t];
        accL[1][t] = v > 0.f ? v : (__expf(v) - 1.f);
    }
    __syncthreads();
    if (t < 64) {
        float y = linb[t];
        for (int c = 0; c < 64; ++c) y = fmaf(accL[1][c], linW[c * 64 + t], y);
        float ss = y * y;
        ss += __shfl_xor(ss, 1);  ss += __shfl_xor(ss, 2);  ss += __shfl_xor(ss, 4);
        ss += __shfl_xor(ss, 8);  ss += __shfl_xor(ss, 16); ss += __shfl_xor(ss, 32);
        float rn = 1.f / fmaxf(sqrtf(ss), 1e-12f);
        outp[(size_t)d * 64 + t] = y * rn;
    }
}

// ---------------------------------------------------------------------------

static inline unsigned gridFor(long n) { return (unsigned)((n + 255) / 256); }

extern "C" void kernel_launch(void* const* d_in, const int* in_sizes, int n_in,
                              void* d_out, int out_size, void* d_ws, size_t ws_size,
                              hipStream_t stream) {
    const float* x_artist = (const float*)d_in[0];
    const float* x_track  = (const float*)d_in[1];
    const float* x_genre  = (const float*)d_in[2];
    const float* enc_Wa = (const float*)d_in[3];  const float* enc_ba = (const float*)d_in[4];
    const float* enc_Wt = (const float*)d_in[5];  const float* enc_bt = (const float*)d_in[6];
    const float* enc_Wg = (const float*)d_in[7];  const float* enc_bg = (const float*)d_in[8];
    const int* src_pt = (const int*)d_in[9];
    const int* dst_pt = (const int*)d_in[10];
    const int* src_tg = (const int*)d_in[11];
    const int* dst_tg = (const int*)d_in[12];
    // layer l=1 slices (hidden never fed back -> only last layer matters)
    const float* Wl_pt   = (const float*)d_in[13] + 64 * 256;
    const float* bl_pt   = (const float*)d_in[14] + 256;
    const float* Wr_pt   = (const float*)d_in[15] + 64 * 256;
    const float* br_pt   = (const float*)d_in[16] + 256;
    const float* att_pt  = (const float*)d_in[17] + 256;
    const float* bias_pt = (const float*)d_in[18] + 64;
    const float* Wl_tg   = (const float*)d_in[19] + 64 * 256;
    const float* bl_tg   = (const float*)d_in[20] + 256;
    const float* Wr_tg   = (const float*)d_in[21] + 64 * 256;
    const float* br_tg   = (const float*)d_in[22] + 256;
    const float* att_tg  = (const float*)d_in[23] + 256;
    const float* bias_tg = (const float*)d_in[24] + 64;
    const float* lin_track_W = (const float*)d_in[25];
    const float* lin_track_b = (const float*)d_in[26];
    const float* lin_genre_W = (const float*)d_in[27];
    const float* lin_genre_b = (const float*)d_in[28];

    float* out = (float*)d_out;

    const int NTOT = NT + NG;

    // ---- workspace: fused (non-aliased, ~369 MB) if ws permits, else R6 alias ----
    const size_t smallBytes =
        ((size_t)(NTOT + 1) * 4 + 255 & ~(size_t)255) * 2 +   // counts, rowptr
        ((size_t)NTOT * 4 + 255 & ~(size_t)255) +             // cursor
        8192 +                                                // part
        ((size_t)(EPT + ETG) * 4) +                           // ssrc
        ((size_t)NT * 4 + 255 & ~(size_t)255) +               // order
        16384 * 2 +                                           // bcnt, bbase
        (size_t)NG * 512 +                                    // gr_tg
        (size_t)(64 + 96 + 96 + 32) * 512 +                   // Bf
        4096 + 65536;                                         // bc + slack
    const size_t needFused = (size_t)NA * 512 + (size_t)NT * 512 * 2 + smallBytes;
    bool fused = ws_size >= needFused;

    char* p = (char*)d_ws;
    auto take = [&](size_t bytes) { char* q = p; p += (bytes + 255) & ~(size_t)255; return q; };

    bf16 *gl_pt, *gr_pt, *gl_tg;
    if (fused) {
        gl_pt = (bf16*)take((size_t)NA * 256 * 2);
        gr_pt = (bf16*)take((size_t)NT * 256 * 2);
        gl_tg = (bf16*)take((size_t)NT * 256 * 2);
    } else {
        char* region = take((size_t)NA * 256 * 2 + (size_t)NT * 256 * 2);
        gl_pt = (bf16*)region;
        gr_pt = (bf16*)(region + (size_t)NA * 256 * 2);
        gl_tg = (bf16*)region;                    // aliases gl_pt/gr_pt (serialized)
    }
    unsigned* counts = (unsigned*)take((size_t)(NTOT + 1) * 4);
    unsigned* rowptr = (unsigned*)take((size_t)(NTOT + 1) * 4);
    unsigned* cursor = (unsigned*)take((size_t)NTOT * 4);
    unsigned* part   = (unsigned*)take((size_t)2048 * 4);
    int*      ssrc   = (int*)take((size_t)(EPT + ETG) * 4);
    int*      order  = (int*)take((size_t)NT * 4);
    unsigned* bcnt   = (unsigned*)take((size_t)DBK * DSB * 4);
    unsigned* bbase  = (unsigned*)take((size_t)DBK * DSB * 4);
    bf16*     gr_tg  = (bf16*)take((size_t)NG * 256 * 2);
    short*    Bf     = (short*)take((size_t)(64 + 96 + 96 + 32) * 256 * 2);
    float*    bc     = (float*)take((size_t)4 * 256 * 4);

    short* BfGLpt = Bf;                       // K=64
    short* BfGRpt = BfGLpt + 64 * 256;        // K=96
    short* BfGLtg = BfGRpt + 96 * 256;        // K=96
    short* BfGRtg = BfGLtg + 96 * 256;        // K=32
    float* bcGLpt = bc;
    float* bcGRpt = bc + 256;
    float* bcGLtg = bc + 512;
    float* bcGRtg = bc + 768;

    dim3 blk(256);

    // ---- all four weight preps in one launch ----
    WP p0 = {enc_Wa, Wl_pt, bl_pt, enc_ba, BfGLpt, bcGLpt, 2, 0};
    WP p1 = {enc_Wt, Wr_pt, br_pt, enc_bt, BfGRpt, bcGRpt, 3, 8};
    WP p2 = {enc_Wt, Wl_tg, bl_tg, enc_bt, BfGLtg, bcGLtg, 3, 20};
    WP p3 = {enc_Wg, Wr_tg, br_tg, enc_bg, BfGRtg, bcGRtg, 1, 32};
    wprep_all<<<36, blk, 0, stream>>>(p0, p1, p2, p3);

    // ---- merged counting sort: concatenated CSR over [pt dsts | tg dsts] ----
    {
        int n = NTOT + 1;
        unsigned sgrid = (unsigned)((n + 1023) / 1024);
        fill_u32<<<gridFor(n), blk, 0, stream>>>(counts, 0u, n);
        histo_all<<<gridFor(EPT + ETG), blk, 0, stream>>>(dst_pt, dst_tg, counts);
        scan_a<<<sgrid, blk, 0, stream>>>(counts, rowptr, part, n);
        scan_a<<<1, blk, 0, stream>>>(part, part, part + 1536, (int)sgrid);
        scan_c<<<gridFor(n), blk, 0, stream>>>(rowptr, part, cursor, n);
        scat_all<<<gridFor(EPT + ETG), blk, 0, stream>>>(src_pt, dst_pt, src_tg, dst_tg,
                                                         cursor, ssrc);
    }

    // ---- degree-sort pt dsts (contention-free: LDS histograms) ----
    deg_cnt  <<<DSB, blk, 0, stream>>>(rowptr, bcnt, NT);
    scan4k   <<<1,   blk, 0, stream>>>(bcnt, bbase);
    deg_place<<<DSB, blk, 0, stream>>>(rowptr, bbase, order, NT);

    if (fused) {
        // all transforms up front (x_track read ONCE for both NT transforms)
        tformf<2><<<(NA + 63) / 64, blk, 0, stream>>>(x_artist, BfGLpt, bcGLpt, gl_pt, NA);
        tformf2  <<<(NT + 63) / 64, blk, 0, stream>>>(x_track, BfGRpt, bcGRpt, gr_pt,
                                                      BfGLtg, bcGLtg, gl_tg, NT);
        tformf<1><<<(NG + 63) / 64, blk, 0, stream>>>(x_genre, BfGRtg, bcGRtg, gr_tg, NG);

        gat_w<<<2048, blk, 0, stream>>>(gl_pt, gr_pt, ssrc, rowptr, order, att_pt, bias_pt,
                                        lin_track_W, lin_track_b, out, NT);
        gat_b<<<NG, blk, 0, stream>>>(gl_tg, gr_tg, ssrc, rowptr + NT, att_tg, bias_tg,
                                      lin_genre_W, lin_genre_b, out + (size_t)NT * 64, NG);
    } else {
        // R6 fallback: aliased buffers, gat_w before tg transforms
        tformf<2><<<(NA + 63) / 64, blk, 0, stream>>>(x_artist, BfGLpt, bcGLpt, gl_pt, NA);
        tformf<3><<<(NT + 63) / 64, blk, 0, stream>>>(x_track,  BfGRpt, bcGRpt, gr_pt, NT);

        gat_w<<<2048, blk, 0, stream>>>(gl_pt, gr_pt, ssrc, rowptr, order, att_pt, bias_pt,
                                        lin_track_W, lin_track_b, out, NT);

        tformf<3><<<(NT + 63) / 64, blk, 0, stream>>>(x_track, BfGLtg, bcGLtg, gl_tg, NT);
        tformf<1><<<(NG + 63) / 64, blk, 0, stream>>>(x_genre, BfGRtg, bcGRtg, gr_tg, NG);

        gat_b<<<NG, blk, 0, stream>>>(gl_tg, gr_tg, ssrc, rowptr + NT, att_tg, bias_tg,
                                      lin_genre_W, lin_genre_b, out + (size_t)NT * 64, NG);
    }
}